// Round 2
// baseline (720.615 us; speedup 1.0000x reference)
//
#include <hip/hip_runtime.h>
#include <math.h>

#define N0c   16
#define NAt   96
#define ORIG  92
#define Fc    64
#define Kc    41
#define Hc    128
#define NCc   3
#define C2    128   // 2F
#define EPSBN 1e-5f
#define JG    4     // j-groups per block
#define JPW   (NAt / JG)   // 24 j's per group

__device__ __forceinline__ float sp_(float x){
    // stable softplus: max(x,0) + log1p(exp(-|x|))
    return fmaxf(x, 0.f) + log1pf(expf(-fabsf(x)));
}
__device__ __forceinline__ float sgm_(float x){
    return 1.f / (1.f + expf(-x));
}

// fea = atom @ emb_W + emb_b   (1536 x 92) @ (92 x 64)
__global__ __launch_bounds__(256) void k_embed(const float* __restrict__ atom,
                                               const float* __restrict__ W,
                                               const float* __restrict__ b,
                                               float* __restrict__ fea){
    int row = blockIdx.x * 4 + (threadIdx.x >> 6);   // wave-uniform row
    int f   = threadIdx.x & 63;
    const float* ar = atom + row * ORIG;
    float acc = b[f];
    #pragma unroll 4
    for (int o = 0; o < ORIG; ++o) acc += ar[o] * W[o * Fc + f];
    fea[row * Fc + f] = acc;
}

// Fused: p1/p2 precompute + pass-1 BN stats.
// block = 512 threads: (jg in [0,4)) x (c in [0,128)); grid = 1536 (b,i) rows.
__global__ __launch_bounds__(512, 2) void k_stats(const float* __restrict__ nbr,
                                                  const int*   __restrict__ adj,
                                                  const float* __restrict__ Wl,
                                                  const float* __restrict__ fea,
                                                  const float* __restrict__ bl,
                                                  float* __restrict__ p1,
                                                  float* __restrict__ p2,
                                                  float* __restrict__ sum1,
                                                  float* __restrict__ sq1){
    int bi = blockIdx.x;
    int c  = threadIdx.x & (C2 - 1);
    int jg = threadIdx.x >> 7;
    __shared__ float sp1[C2], sp2[C2];
    __shared__ float rs[JG][C2], rq[JG][C2];

    if (jg == 0){
        const float* fr = fea + bi * Fc;
        float a1 = bl[c], a2 = 0.f;
        #pragma unroll 8
        for (int f = 0; f < Fc; ++f){
            float fv = fr[f];                 // wave-uniform -> scalar load
            a1 += fv * Wl[f * C2 + c];
            a2 += fv * Wl[(Fc + f) * C2 + c];
        }
        sp1[c] = a1; sp2[c] = a2;
        p1[bi * C2 + c] = a1;                 // k_apply consumes these
        p2[bi * C2 + c] = a2;
    }

    float w3[Kc];                             // register-resident W3 column
    #pragma unroll
    for (int k = 0; k < Kc; ++k) w3[k] = Wl[(C2 + k) * C2 + c];

    __syncthreads();
    float pc1 = sp1[c], pc2 = sp2[c];
    const float* nb = nbr + (size_t)bi * (NAt * Kc);
    const int*   aj = adj + bi * NAt;

    float s = 0.f, sq = 0.f;
    for (int j = jg * JPW; j < jg * JPW + JPW; ++j){
        const float* nr = nb + j * Kc;        // wave-uniform -> s_loads
        float ajf = (float)aj[j];
        float d0 = 0.f, d1 = 0.f, d2 = 0.f, d3 = 0.f;
        #pragma unroll
        for (int k = 0; k < 40; k += 4){
            d0 += nr[k    ] * w3[k    ];
            d1 += nr[k + 1] * w3[k + 1];
            d2 += nr[k + 2] * w3[k + 2];
            d3 += nr[k + 3] * w3[k + 3];
        }
        d0 += nr[40] * w3[40];
        float g = pc1 + ajf * pc2 + ((d0 + d1) + (d2 + d3));
        s  += g;
        sq += g * g;
    }
    rs[jg][c] = s; rq[jg][c] = sq;
    __syncthreads();
    if (jg == 0){
        s  = rs[0][c] + rs[1][c] + rs[2][c] + rs[3][c];
        sq = rq[0][c] + rq[1][c] + rq[2][c] + rq[3][c];
        atomicAdd(&sum1[c], s);
        atomicAdd(&sq1[c],  sq);
    }
}

// finalize BN affine: a = g/sqrt(var+eps), bb = b - mean*a  (also used for BN2)
__global__ void k_fin(const float* __restrict__ sum, const float* __restrict__ sq,
                      const float* __restrict__ g,   const float* __restrict__ b,
                      float* __restrict__ a, float* __restrict__ bb, float invM){
    int c = threadIdx.x;
    float m = sum[c] * invM;
    float v = sq[c] * invM - m * m;
    float ac = g[c] * rsqrtf(v + EPSBN);
    a[c]  = ac;
    bb[c] = b[c] - m * ac;
}

// Pass 2: recompute gated, BN1, sigmoid*softplus, sum over j; BN2 stats.
// block = 256 threads: (jg in [0,4)) x (f in [0,64)); grid = 1536.
__global__ __launch_bounds__(256, 2) void k_apply(const float* __restrict__ nbr,
                                                  const int*   __restrict__ adj,
                                                  const float* __restrict__ Wl,
                                                  const float* __restrict__ p1,
                                                  const float* __restrict__ p2,
                                                  const float* __restrict__ a1,
                                                  const float* __restrict__ bb1,
                                                  float* __restrict__ summed,
                                                  float* __restrict__ sum2,
                                                  float* __restrict__ sq2){
    int bi = blockIdx.x;
    int f  = threadIdx.x & 63;
    int jg = threadIdx.x >> 6;
    __shared__ float red[JG][Fc];

    float wa[Kc], wb[Kc];                     // register-resident W3 columns
    #pragma unroll
    for (int k = 0; k < Kc; ++k){
        wa[k] = Wl[(C2 + k) * C2 + f];
        wb[k] = Wl[(C2 + k) * C2 + Fc + f];
    }
    float pa1 = p1[bi * C2 + f],      pa2 = p2[bi * C2 + f];
    float pb1 = p1[bi * C2 + Fc + f], pb2 = p2[bi * C2 + Fc + f];
    float A1 = a1[f],      B1 = bb1[f];
    float A2 = a1[Fc + f], B2 = bb1[Fc + f];
    const float* nb = nbr + (size_t)bi * (NAt * Kc);
    const int*   aj = adj + bi * NAt;

    float acc = 0.f;
    for (int j = jg * JPW; j < jg * JPW + JPW; ++j){
        const float* nr = nb + j * Kc;        // wave-uniform -> s_loads
        float ajf = (float)aj[j];
        float f0 = 0.f, f1 = 0.f, c0 = 0.f, c1 = 0.f;
        #pragma unroll
        for (int k = 0; k < 40; k += 2){
            float n0 = nr[k], n1 = nr[k + 1];
            f0 += n0 * wa[k];     f1 += n1 * wa[k + 1];
            c0 += n0 * wb[k];     c1 += n1 * wb[k + 1];
        }
        { float n0 = nr[40]; f0 += n0 * wa[40]; c0 += n0 * wb[40]; }
        float gf = (pa1 + ajf * pa2 + (f0 + f1)) * A1 + B1;
        float gc = (pb1 + ajf * pb2 + (c0 + c1)) * A2 + B2;
        acc += sgm_(gf) * sp_(gc);
    }
    red[jg][f] = acc;
    __syncthreads();
    if (jg == 0){
        acc = red[0][f] + red[1][f] + red[2][f] + red[3][f];
        summed[bi * Fc + f] = acc;
        atomicAdd(&sum2[f], acc);
        atomicAdd(&sq2[f],  acc * acc);
    }
}

// fea = softplus(fea + BN2(summed))
__global__ __launch_bounds__(256) void k_update(float* __restrict__ fea,
                                                const float* __restrict__ summed,
                                                const float* __restrict__ a2,
                                                const float* __restrict__ bb2){
    int idx = blockIdx.x * 256 + threadIdx.x;
    int f   = idx & 63;
    float v = fea[idx] + summed[idx] * a2[f] + bb2[f];
    fea[idx] = sp_(v);
}

// crys = mean_i fea; out = softplus(softplus(crys)@fcW + fcb) @ outW + outb
__global__ __launch_bounds__(128) void k_final(const float* __restrict__ fea,
                                               const float* __restrict__ fcW,
                                               const float* __restrict__ fcb,
                                               const float* __restrict__ outW,
                                               const float* __restrict__ outb,
                                               float* __restrict__ out){
    int b = blockIdx.x;
    int t = threadIdx.x;
    __shared__ float spc[Fc];
    __shared__ float red[Hc];
    if (t < Fc){
        float s = 0.f;
        for (int i = 0; i < NAt; ++i) s += fea[(b * NAt + i) * Fc + t];
        spc[t] = sp_(s * (1.f / NAt));
    }
    __syncthreads();
    float h = fcb[t];
    #pragma unroll 4
    for (int f = 0; f < Fc; ++f) h += spc[f] * fcW[f * Hc + t];
    h = sp_(h);
    red[t] = h * outW[t];
    __syncthreads();
    for (int off = 64; off > 0; off >>= 1){
        if (t < off) red[t] += red[t + off];
        __syncthreads();
    }
    if (t == 0) out[b] = red[0] + outb[0];
}

extern "C" void kernel_launch(void* const* d_in, const int* in_sizes, int n_in,
                              void* d_out, int out_size, void* d_ws, size_t ws_size,
                              hipStream_t stream){
    const float* atom  = (const float*)d_in[0];
    const float* nbr   = (const float*)d_in[1];
    const int*   adj   = (const int*)  d_in[2];
    const float* embW  = (const float*)d_in[3];
    const float* embB  = (const float*)d_in[4];
    const float* convW = (const float*)d_in[5];
    const float* convB = (const float*)d_in[6];
    const float* bn1g  = (const float*)d_in[7];
    const float* bn1b  = (const float*)d_in[8];
    const float* bn2g  = (const float*)d_in[9];
    const float* bn2b  = (const float*)d_in[10];
    const float* fcW   = (const float*)d_in[11];
    const float* fcb   = (const float*)d_in[12];
    const float* outW  = (const float*)d_in[13];
    const float* outb  = (const float*)d_in[14];
    float* out = (float*)d_out;
    float* ws  = (float*)d_ws;

    const int ROWS = N0c * NAt;            // 1536
    float* fea    = ws;                    // 98304
    float* p1     = ws + 98304;            // 196608
    float* p2     = ws + 294912;           // 196608
    float* summed = ws + 491520;           // 98304
    float* S      = ws + 589824;           // stats block
    float* sum1 = S,       *sq1 = S + 128;
    float* sum2 = S + 256, *sq2 = S + 320;
    float* a1   = S + 384, *bb1 = S + 512;
    float* a2   = S + 640, *bb2 = S + 704;

    k_embed<<<ROWS / 4, 256, 0, stream>>>(atom, embW, embB, fea);

    for (int l = 0; l < NCc; ++l){
        const float* Wl = convW + (size_t)l * 169 * C2;
        const float* bl = convB + l * C2;
        hipMemsetAsync(S, 0, 384 * sizeof(float), stream);   // sum1,sq1,sum2,sq2
        k_stats<<<ROWS, 512, 0, stream>>>(nbr, adj, Wl, fea, bl, p1, p2, sum1, sq1);
        k_fin  <<<1, C2, 0, stream>>>(sum1, sq1, bn1g + l * C2, bn1b + l * C2,
                                      a1, bb1, 1.f / (float)(N0c * NAt * NAt));
        k_apply<<<ROWS, 256, 0, stream>>>(nbr, adj, Wl, p1, p2, a1, bb1,
                                          summed, sum2, sq2);
        k_fin  <<<1, Fc, 0, stream>>>(sum2, sq2, bn2g + l * Fc, bn2b + l * Fc,
                                      a2, bb2, 1.f / (float)(N0c * NAt));
        k_update<<<ROWS * Fc / 256, 256, 0, stream>>>(fea, summed, a2, bb2);
    }

    k_final<<<N0c, Hc, 0, stream>>>(fea, fcW, fcb, outW, outb, out);
}

// Round 3
// 499.939 us; speedup vs baseline: 1.4414x; 1.4414x over previous
//
#include <hip/hip_runtime.h>
#include <math.h>

#define N0c   16
#define NAt   96
#define ORIG  92
#define Fc    64
#define Kc    41
#define Hc    128
#define NCc   3
#define C2    128   // 2F
#define EPSBN 1e-5f
#define JG    4     // j-groups per block
#define JPW   (NAt / JG)   // 24 j's per group

__device__ __forceinline__ float sp_(float x){
    // stable softplus: max(x,0) + log1p(exp(-|x|))
    return fmaxf(x, 0.f) + log1pf(expf(-fabsf(x)));
}
__device__ __forceinline__ float sgm_(float x){
    return 1.f / (1.f + expf(-x));
}

// fea = atom @ emb_W + emb_b   (1536 x 92) @ (92 x 64)
__global__ __launch_bounds__(256) void k_embed(const float* __restrict__ atom,
                                               const float* __restrict__ W,
                                               const float* __restrict__ b,
                                               float* __restrict__ fea){
    int row = blockIdx.x * 4 + (threadIdx.x >> 6);   // wave-uniform row
    int f   = threadIdx.x & 63;
    const float* ar = atom + row * ORIG;
    float acc = b[f];
    #pragma unroll 4
    for (int o = 0; o < ORIG; ++o) acc += ar[o] * W[o * Fc + f];
    fea[row * Fc + f] = acc;
}

// Fused: p1/p2 precompute + pass-1 BN stats.
// block = 512 threads: (jg in [0,4)) x (c in [0,128)); grid = 1536 (b,i) rows.
// jg MUST be an SGPR (readfirstlane) so nbr-row loads stay scalar s_loads.
__global__ __launch_bounds__(512, 2) void k_stats(const float* __restrict__ nbr,
                                                  const int*   __restrict__ adj,
                                                  const float* __restrict__ Wl,
                                                  const float* __restrict__ fea,
                                                  const float* __restrict__ bl,
                                                  float* __restrict__ p1,
                                                  float* __restrict__ p2,
                                                  float* __restrict__ sum1,
                                                  float* __restrict__ sq1){
    int bi = blockIdx.x;
    int c  = threadIdx.x & (C2 - 1);
    // tid>>7 is wave-uniform (waves are consecutive 64 threads); force SGPR so
    // the compiler's divergence analysis keeps nbr addresses scalar.
    int jg = __builtin_amdgcn_readfirstlane(threadIdx.x >> 7);
    __shared__ float sp1[C2], sp2[C2];
    __shared__ float rs[JG][C2], rq[JG][C2];

    if (jg == 0){
        const float* fr = fea + bi * Fc;
        float a1 = bl[c], a2 = 0.f;
        #pragma unroll 8
        for (int f = 0; f < Fc; ++f){
            float fv = fr[f];                 // wave-uniform -> scalar load
            a1 += fv * Wl[f * C2 + c];
            a2 += fv * Wl[(Fc + f) * C2 + c];
        }
        sp1[c] = a1; sp2[c] = a2;
        p1[bi * C2 + c] = a1;                 // k_apply consumes these
        p2[bi * C2 + c] = a2;
    }

    float w3[Kc];                             // register-resident W3 column
    #pragma unroll
    for (int k = 0; k < Kc; ++k) w3[k] = Wl[(C2 + k) * C2 + c];

    __syncthreads();
    float pc1 = sp1[c], pc2 = sp2[c];
    const float* nb = nbr + (size_t)bi * (NAt * Kc);
    const int*   aj = adj + bi * NAt;

    float s = 0.f, sq = 0.f;
    int j0 = jg * JPW;
    for (int j = j0; j < j0 + JPW; ++j){
        const float* nr = nb + j * Kc;        // wave-uniform -> s_loads
        float ajf = (float)aj[j];
        float d0 = 0.f, d1 = 0.f, d2 = 0.f, d3 = 0.f;
        #pragma unroll
        for (int k = 0; k < 40; k += 4){
            d0 += nr[k    ] * w3[k    ];
            d1 += nr[k + 1] * w3[k + 1];
            d2 += nr[k + 2] * w3[k + 2];
            d3 += nr[k + 3] * w3[k + 3];
        }
        d0 += nr[40] * w3[40];
        float g = pc1 + ajf * pc2 + ((d0 + d1) + (d2 + d3));
        s  += g;
        sq += g * g;
    }
    rs[jg][c] = s; rq[jg][c] = sq;
    __syncthreads();
    if (jg == 0){
        s  = rs[0][c] + rs[1][c] + rs[2][c] + rs[3][c];
        sq = rq[0][c] + rq[1][c] + rq[2][c] + rq[3][c];
        atomicAdd(&sum1[c], s);
        atomicAdd(&sq1[c],  sq);
    }
}

// finalize BN affine: a = g/sqrt(var+eps), bb = b - mean*a  (also used for BN2)
__global__ void k_fin(const float* __restrict__ sum, const float* __restrict__ sq,
                      const float* __restrict__ g,   const float* __restrict__ b,
                      float* __restrict__ a, float* __restrict__ bb, float invM){
    int c = threadIdx.x;
    float m = sum[c] * invM;
    float v = sq[c] * invM - m * m;
    float ac = g[c] * rsqrtf(v + EPSBN);
    a[c]  = ac;
    bb[c] = b[c] - m * ac;
}

// Pass 2: recompute gated, BN1, sigmoid*softplus, sum over j; BN2 stats.
// block = 256 threads: (jg in [0,4)) x (f in [0,64)); grid = 1536.
__global__ __launch_bounds__(256, 2) void k_apply(const float* __restrict__ nbr,
                                                  const int*   __restrict__ adj,
                                                  const float* __restrict__ Wl,
                                                  const float* __restrict__ p1,
                                                  const float* __restrict__ p2,
                                                  const float* __restrict__ a1,
                                                  const float* __restrict__ bb1,
                                                  float* __restrict__ summed,
                                                  float* __restrict__ sum2,
                                                  float* __restrict__ sq2){
    int bi = blockIdx.x;
    int f  = threadIdx.x & 63;
    int jg = __builtin_amdgcn_readfirstlane(threadIdx.x >> 6);  // SGPR, see k_stats
    __shared__ float red[JG][Fc];

    float wa[Kc], wb[Kc];                     // register-resident W3 columns
    #pragma unroll
    for (int k = 0; k < Kc; ++k){
        wa[k] = Wl[(C2 + k) * C2 + f];
        wb[k] = Wl[(C2 + k) * C2 + Fc + f];
    }
    float pa1 = p1[bi * C2 + f],      pa2 = p2[bi * C2 + f];
    float pb1 = p1[bi * C2 + Fc + f], pb2 = p2[bi * C2 + Fc + f];
    float A1 = a1[f],      B1 = bb1[f];
    float A2 = a1[Fc + f], B2 = bb1[Fc + f];
    const float* nb = nbr + (size_t)bi * (NAt * Kc);
    const int*   aj = adj + bi * NAt;

    float acc = 0.f;
    int j0 = jg * JPW;
    for (int j = j0; j < j0 + JPW; ++j){
        const float* nr = nb + j * Kc;        // wave-uniform -> s_loads
        float ajf = (float)aj[j];
        float f0 = 0.f, f1 = 0.f, c0 = 0.f, c1 = 0.f;
        #pragma unroll
        for (int k = 0; k < 40; k += 2){
            float n0 = nr[k], n1 = nr[k + 1];
            f0 += n0 * wa[k];     f1 += n1 * wa[k + 1];
            c0 += n0 * wb[k];     c1 += n1 * wb[k + 1];
        }
        { float n0 = nr[40]; f0 += n0 * wa[40]; c0 += n0 * wb[40]; }
        float gf = (pa1 + ajf * pa2 + (f0 + f1)) * A1 + B1;
        float gc = (pb1 + ajf * pb2 + (c0 + c1)) * A2 + B2;
        acc += sgm_(gf) * sp_(gc);
    }
    red[jg][f] = acc;
    __syncthreads();
    if (jg == 0){
        acc = red[0][f] + red[1][f] + red[2][f] + red[3][f];
        summed[bi * Fc + f] = acc;
        atomicAdd(&sum2[f], acc);
        atomicAdd(&sq2[f],  acc * acc);
    }
}

// fea = softplus(fea + BN2(summed))
__global__ __launch_bounds__(256) void k_update(float* __restrict__ fea,
                                                const float* __restrict__ summed,
                                                const float* __restrict__ a2,
                                                const float* __restrict__ bb2){
    int idx = blockIdx.x * 256 + threadIdx.x;
    int f   = idx & 63;
    float v = fea[idx] + summed[idx] * a2[f] + bb2[f];
    fea[idx] = sp_(v);
}

// crys = mean_i fea; out = softplus(softplus(crys)@fcW + fcb) @ outW + outb
__global__ __launch_bounds__(128) void k_final(const float* __restrict__ fea,
                                               const float* __restrict__ fcW,
                                               const float* __restrict__ fcb,
                                               const float* __restrict__ outW,
                                               const float* __restrict__ outb,
                                               float* __restrict__ out){
    int b = blockIdx.x;
    int t = threadIdx.x;
    __shared__ float spc[Fc];
    __shared__ float red[Hc];
    if (t < Fc){
        float s = 0.f;
        for (int i = 0; i < NAt; ++i) s += fea[(b * NAt + i) * Fc + t];
        spc[t] = sp_(s * (1.f / NAt));
    }
    __syncthreads();
    float h = fcb[t];
    #pragma unroll 4
    for (int f = 0; f < Fc; ++f) h += spc[f] * fcW[f * Hc + t];
    h = sp_(h);
    red[t] = h * outW[t];
    __syncthreads();
    for (int off = 64; off > 0; off >>= 1){
        if (t < off) red[t] += red[t + off];
        __syncthreads();
    }
    if (t == 0) out[b] = red[0] + outb[0];
}

extern "C" void kernel_launch(void* const* d_in, const int* in_sizes, int n_in,
                              void* d_out, int out_size, void* d_ws, size_t ws_size,
                              hipStream_t stream){
    const float* atom  = (const float*)d_in[0];
    const float* nbr   = (const float*)d_in[1];
    const int*   adj   = (const int*)  d_in[2];
    const float* embW  = (const float*)d_in[3];
    const float* embB  = (const float*)d_in[4];
    const float* convW = (const float*)d_in[5];
    const float* convB = (const float*)d_in[6];
    const float* bn1g  = (const float*)d_in[7];
    const float* bn1b  = (const float*)d_in[8];
    const float* bn2g  = (const float*)d_in[9];
    const float* bn2b  = (const float*)d_in[10];
    const float* fcW   = (const float*)d_in[11];
    const float* fcb   = (const float*)d_in[12];
    const float* outW  = (const float*)d_in[13];
    const float* outb  = (const float*)d_in[14];
    float* out = (float*)d_out;
    float* ws  = (float*)d_ws;

    const int ROWS = N0c * NAt;            // 1536
    float* fea    = ws;                    // 98304
    float* p1     = ws + 98304;            // 196608
    float* p2     = ws + 294912;           // 196608
    float* summed = ws + 491520;           // 98304
    float* S      = ws + 589824;           // stats block
    float* sum1 = S,       *sq1 = S + 128;
    float* sum2 = S + 256, *sq2 = S + 320;
    float* a1   = S + 384, *bb1 = S + 512;
    float* a2   = S + 640, *bb2 = S + 704;

    k_embed<<<ROWS / 4, 256, 0, stream>>>(atom, embW, embB, fea);

    for (int l = 0; l < NCc; ++l){
        const float* Wl = convW + (size_t)l * 169 * C2;
        const float* bl = convB + l * C2;
        hipMemsetAsync(S, 0, 384 * sizeof(float), stream);   // sum1,sq1,sum2,sq2
        k_stats<<<ROWS, 512, 0, stream>>>(nbr, adj, Wl, fea, bl, p1, p2, sum1, sq1);
        k_fin  <<<1, C2, 0, stream>>>(sum1, sq1, bn1g + l * C2, bn1b + l * C2,
                                      a1, bb1, 1.f / (float)(N0c * NAt * NAt));
        k_apply<<<ROWS, 256, 0, stream>>>(nbr, adj, Wl, p1, p2, a1, bb1,
                                          summed, sum2, sq2);
        k_fin  <<<1, Fc, 0, stream>>>(sum2, sq2, bn2g + l * Fc, bn2b + l * Fc,
                                      a2, bb2, 1.f / (float)(N0c * NAt));
        k_update<<<ROWS * Fc / 256, 256, 0, stream>>>(fea, summed, a2, bb2);
    }

    k_final<<<N0c, Hc, 0, stream>>>(fea, fcW, fcb, outW, outb, out);
}